// Round 1
// baseline (1374.755 us; speedup 1.0000x reference)
//
#include <hip/hip_runtime.h>
#include <hip/hip_bf16.h>

typedef __bf16 bf16x8 __attribute__((ext_vector_type(8)));
typedef float  f32x16 __attribute__((ext_vector_type(16)));
typedef unsigned short ushort_t;

#define B_   32
#define S_   2048
#define D_   1024
#define A_   1024
#define ADD_ 256
#define H_   1024

// ---------- fast transcendentals (accurate to ~1e-6 rel; bf16 noise dominates) ----------
__device__ __forceinline__ float fast_rcp(float x){ return __builtin_amdgcn_rcpf(x); }
__device__ __forceinline__ float fast_sig(float x){ return fast_rcp(1.f + __expf(-x)); }
__device__ __forceinline__ float fast_tanh(float x){
  float ax = fabsf(x);
  float e  = __expf(-2.f * ax);
  float t  = (1.f - e) * fast_rcp(1.f + e);
  return copysignf(t, x);
}
__device__ __forceinline__ unsigned bfbits(float x){
  return (unsigned)__builtin_bit_cast(ushort_t, (__bf16)x);
}

// ---------- convert Wh (f32) -> bf16 ----------
__global__ __launch_bounds__(256) void cvt_wh_k(const float* __restrict__ Wh,
                                                ushort_t* __restrict__ whbf){
  int i = blockIdx.x * 256 + threadIdx.x;           // over 1024*1024/4
  float4 f = reinterpret_cast<const float4*>(Wh)[i];
  uint2 u;
  u.x = bfbits(f.x) | (bfbits(f.y) << 16);
  u.y = bfbits(f.z) | (bfbits(f.w) << 16);
  reinterpret_cast<uint2*>(whbf)[i] = u;
}

// ---------- copy h0,c0,h1,c1 -> d_out hidden regions (scatter overwrites later) ----------
__global__ __launch_bounds__(256) void copy4_k(const float* __restrict__ h0,
                                               const float* __restrict__ c0,
                                               const float* __restrict__ h1,
                                               const float* __restrict__ c1,
                                               float* __restrict__ dout){
  int i = blockIdx.x * 256 + threadIdx.x;           // < 4*32768
  int which = i >> 15, r = i & 32767;
  const float* src = which == 0 ? h0 : which == 1 ? c0 : which == 2 ? h1 : c1;
  dout[32768 + i] = src[r];
}

// ---------- fused score GEMM: sraw[g][s] += sum_a tanh(hist·Wh^T + ca)·v ----------
// tile: BM=128 rows(b,s), BN=128 cols(a), BK=64; 4 waves (2x2), wave tile 64x64
// via 2x2 frags of v_mfma_f32_32x32x16_bf16. LDS XOR-swizzled (we control both sides).
__global__ __launch_bounds__(256) void score_gemm(
    const float* __restrict__ hist_theirs, const float* __restrict__ hist_ours,
    const ushort_t* __restrict__ whbf, const float* __restrict__ ca,
    const float* __restrict__ vvec, float* __restrict__ sraw){
  __shared__ uint4 As4[128 * 8];   // 128 rows x 8 slots(16B) = 64 bf16/row
  __shared__ uint4 Bs4[128 * 8];

  const int t  = threadIdx.x;
  const int bx = blockIdx.x;            // 0..7   col tile
  const int by = blockIdx.y;            // 0..1023 row tile
  const int g  = by >> 4;               // 16 row-tiles per g
  const int b  = g & 31;
  const float* hist = (g < 32 ? hist_theirs : hist_ours) + (size_t)b * S_ * D_;
  const int srow0 = (by & 15) * 128;

  const int sr = t >> 1;                // staging row 0..127
  const int sh = t & 1;                 // staging half (32 k each)
  const float*    asrc = hist + (size_t)(srow0 + sr) * D_ + sh * 32;
  const ushort_t* bsrc = whbf + (size_t)(bx * 128 + sr) * D_ + sh * 32;

  const int w = t >> 6, lane = t & 63;
  const int wr = w >> 1, wc = w & 1;
  const int l31 = lane & 31, lhi = lane >> 5;

  f32x16 acc[2][2];
  #pragma unroll
  for (int m = 0; m < 2; m++)
    #pragma unroll
    for (int n = 0; n < 2; n++)
      #pragma unroll
      for (int i = 0; i < 16; i++) acc[m][n][i] = 0.f;

  for (int kc = 0; kc < D_; kc += 64) {
    { // stage A: 32 f32 -> 32 bf16 (RNE), 4 swizzled 16B slots
      const float* p = asrc + kc;
      float4 f[8];
      #pragma unroll
      for (int i = 0; i < 8; i++) f[i] = *reinterpret_cast<const float4*>(p + i * 4);
      #pragma unroll
      for (int j = 0; j < 4; j++) {
        bf16x8 o;
        float4 u = f[2 * j], v2 = f[2 * j + 1];
        o[0] = (__bf16)u.x;  o[1] = (__bf16)u.y;  o[2] = (__bf16)u.z;  o[3] = (__bf16)u.w;
        o[4] = (__bf16)v2.x; o[5] = (__bf16)v2.y; o[6] = (__bf16)v2.z; o[7] = (__bf16)v2.w;
        *reinterpret_cast<bf16x8*>(&As4[sr * 8 + ((sh * 4 + j) ^ (sr & 7))]) = o;
      }
    }
    { // stage B: already bf16, straight 16B copies
      const ushort_t* p = bsrc + kc;
      #pragma unroll
      for (int j = 0; j < 4; j++)
        Bs4[sr * 8 + ((sh * 4 + j) ^ (sr & 7))] = *reinterpret_cast<const uint4*>(p + j * 8);
    }
    __syncthreads();
    #pragma unroll
    for (int ks = 0; ks < 4; ks++) {      // 4 K-steps of 16
      bf16x8 af[2], bfr[2];
      #pragma unroll
      for (int m = 0; m < 2; m++) {
        int ar = wr * 64 + m * 32 + l31;
        af[m] = *reinterpret_cast<const bf16x8*>(&As4[ar * 8 + ((ks * 2 + lhi) ^ (ar & 7))]);
      }
      #pragma unroll
      for (int n = 0; n < 2; n++) {
        int br = wc * 64 + n * 32 + l31;
        bfr[n] = *reinterpret_cast<const bf16x8*>(&Bs4[br * 8 + ((ks * 2 + lhi) ^ (br & 7))]);
      }
      #pragma unroll
      for (int m = 0; m < 2; m++)
        #pragma unroll
        for (int n = 0; n < 2; n++)
          acc[m][n] = __builtin_amdgcn_mfma_f32_32x32x16_bf16(af[m], bfr[n], acc[m][n], 0, 0, 0);
    }
    __syncthreads();
  }

  // epilogue: tanh(ha+ca)*v, reduce over this block's 128 cols, atomicAdd partials
  float cav[2], vv[2];
  #pragma unroll
  for (int n = 0; n < 2; n++) {
    int col = bx * 128 + wc * 64 + n * 32 + l31;
    cav[n] = ca[b * A_ + col];
    vv[n]  = vvec[col];
  }
  #pragma unroll
  for (int m = 0; m < 2; m++) {
    float ts[16];
    #pragma unroll
    for (int r = 0; r < 16; r++) ts[r] = 0.f;
    #pragma unroll
    for (int n = 0; n < 2; n++)
      #pragma unroll
      for (int r = 0; r < 16; r++)
        ts[r] += fast_tanh(acc[m][n][r] + cav[n]) * vv[n];
    #pragma unroll
    for (int off = 1; off < 32; off <<= 1)
      #pragma unroll
      for (int r = 0; r < 16; r++)
        ts[r] += __shfl_xor(ts[r], off, 64);
    if (l31 == 0) {
      int rb = srow0 + wr * 64 + m * 32 + lhi * 4;   // C layout: row=(r&3)+8*(r>>2)+4*lhi
      #pragma unroll
      for (int r = 0; r < 16; r++) {
        int row = rb + (r & 3) + 8 * (r >> 2);
        atomicAdd(&sraw[(size_t)g * S_ + row], ts[r]);
      }
    }
  }
}

// ---------- masked softmax over S per g; writes p (ws) and score outputs ----------
__global__ __launch_bounds__(256) void softmax_k(
    const float* __restrict__ sraw, const int* __restrict__ len_theirs,
    const int* __restrict__ len_ours, float* __restrict__ p, float* __restrict__ dout){
  const int g = blockIdx.x, t = threadIdx.x;
  const int len = (g < 32) ? len_theirs[g] : len_ours[g - 32];
  const float* row = sraw + (size_t)g * S_;
  float vals[8];
  #pragma unroll
  for (int i = 0; i < 8; i++) vals[i] = row[t * 8 + i];
  float mx = -1e30f;
  #pragma unroll
  for (int i = 0; i < 8; i++) if (t * 8 + i < len) mx = fmaxf(mx, vals[i]);
  #pragma unroll
  for (int off = 1; off < 64; off <<= 1) mx = fmaxf(mx, __shfl_xor(mx, off, 64));
  __shared__ float redm[4], reds[4];
  if ((t & 63) == 0) redm[t >> 6] = mx;
  __syncthreads();
  mx = fmaxf(fmaxf(redm[0], redm[1]), fmaxf(redm[2], redm[3]));
  float e[8]; float sum = 0.f;
  #pragma unroll
  for (int i = 0; i < 8; i++) {
    int s = t * 8 + i;
    e[i] = (s < len) ? __expf(vals[i] - mx) : 0.f;
    sum += e[i];
  }
  #pragma unroll
  for (int off = 1; off < 64; off <<= 1) sum += __shfl_xor(sum, off, 64);
  if ((t & 63) == 0) reds[t >> 6] = sum;
  __syncthreads();
  sum = reds[0] + reds[1] + reds[2] + reds[3];
  float rs = fast_rcp(sum);
  float* pd = p + (size_t)g * S_;
  float* od = (g < 32) ? (dout + 163840 + (size_t)g * S_)
                       : (dout + 229376 + (size_t)(g - 32) * S_);
  #pragma unroll
  for (int i = 0; i < 8; i++) {
    float pv = e[i] * rs;
    pd[t * 8 + i] = pv;
    od[t * 8 + i] = pv;
  }
}

// ---------- att[g][d] = sum_s p[g,s]*hist[g,s,d]  (HBM-bound) ----------
__global__ __launch_bounds__(256) void att_k(
    const float* __restrict__ hist_theirs, const float* __restrict__ hist_ours,
    const float* __restrict__ p, float* __restrict__ att){
  const int g = blockIdx.x, ch = blockIdx.y, t = threadIdx.x;
  const float* hist = (g < 32 ? hist_theirs : hist_ours) + (size_t)(g & 31) * S_ * D_;
  const int s0 = ch * 128;
  __shared__ float ps[128];
  if (t < 128) ps[t] = p[(size_t)g * S_ + s0 + t];
  __syncthreads();
  float ax = 0.f, ay = 0.f, az = 0.f, aw = 0.f;
  const float* hp = hist + (size_t)s0 * D_ + t * 4;
  #pragma unroll 4
  for (int i = 0; i < 128; i++) {
    float4 hv = *reinterpret_cast<const float4*>(hp + (size_t)i * D_);
    float wgt = ps[i];
    ax += wgt * hv.x; ay += wgt * hv.y; az += wgt * hv.z; aw += wgt * hv.w;
  }
  float* ad = att + (size_t)g * D_ + t * 4;
  atomicAdd(ad + 0, ax); atomicAdd(ad + 1, ay);
  atomicAdd(ad + 2, az); atomicAdd(ad + 3, aw);
}

// ---------- generic small-M GEMM: out[b][j] = act( X·W^T + bias ), M=32 ----------
// wave handles 2 consecutive j; lanes slice K by float4; butterfly reduce.
__global__ __launch_bounds__(256) void gemm_small(
    const float* __restrict__ X1, int ldx1, const float* __restrict__ W1, int K1,
    const float* __restrict__ X2, int ldx2, const float* __restrict__ W2, int K2,
    const float* __restrict__ b1, const float* __restrict__ b2,
    float* __restrict__ out, int ldo, int N, int act){
  const int lane = threadIdx.x & 63;
  const int wv   = blockIdx.x * 4 + (threadIdx.x >> 6);
  const int j0   = wv * 2;
  if (j0 >= N) return;
  float acc0[32], acc1[32];
  #pragma unroll
  for (int i = 0; i < 32; i++) { acc0[i] = 0.f; acc1[i] = 0.f; }
  {
    const float* w0p = W1 + (size_t)j0 * K1;
    const float* w1p = W1 + (size_t)(j0 + 1) * K1;
    for (int kc = lane * 4; kc < K1; kc += 256) {
      float4 w0 = *reinterpret_cast<const float4*>(w0p + kc);
      float4 w1 = *reinterpret_cast<const float4*>(w1p + kc);
      #pragma unroll
      for (int bb = 0; bb < 32; bb++) {
        float4 xv = *reinterpret_cast<const float4*>(X1 + (size_t)bb * ldx1 + kc);
        acc0[bb] += w0.x * xv.x + w0.y * xv.y + w0.z * xv.z + w0.w * xv.w;
        acc1[bb] += w1.x * xv.x + w1.y * xv.y + w1.z * xv.z + w1.w * xv.w;
      }
    }
  }
  if (W2) {
    const float* w0p = W2 + (size_t)j0 * K2;
    const float* w1p = W2 + (size_t)(j0 + 1) * K2;
    for (int kc = lane * 4; kc < K2; kc += 256) {
      float4 w0 = *reinterpret_cast<const float4*>(w0p + kc);
      float4 w1 = *reinterpret_cast<const float4*>(w1p + kc);
      #pragma unroll
      for (int bb = 0; bb < 32; bb++) {
        float4 xv = *reinterpret_cast<const float4*>(X2 + (size_t)bb * ldx2 + kc);
        acc0[bb] += w0.x * xv.x + w0.y * xv.y + w0.z * xv.z + w0.w * xv.w;
        acc1[bb] += w1.x * xv.x + w1.y * xv.y + w1.z * xv.z + w1.w * xv.w;
      }
    }
  }
  #pragma unroll
  for (int off = 1; off < 64; off <<= 1)
    #pragma unroll
    for (int bb = 0; bb < 32; bb++) {
      acc0[bb] += __shfl_xor(acc0[bb], off, 64);
      acc1[bb] += __shfl_xor(acc1[bb], off, 64);
    }
  float r0 = 0.f, r1 = 0.f;
  #pragma unroll
  for (int bb = 0; bb < 32; bb++) {
    if ((lane & 31) == bb) { r0 = acc0[bb]; r1 = acc1[bb]; }  // static idx, cndmask
  }
  if (lane < 32) {
    float bias0 = (b1 ? b1[j0] : 0.f) + (b2 ? b2[j0] : 0.f);
    float bias1 = (b1 ? b1[j0 + 1] : 0.f) + (b2 ? b2[j0 + 1] : 0.f);
    float v0 = r0 + bias0, v1 = r1 + bias1;
    if (act == 1) { v0 = fast_tanh(v0); v1 = fast_tanh(v1); }
    out[(size_t)lane * ldo + j0]     = v0;
    out[(size_t)lane * ldo + j0 + 1] = v1;
  }
}

// ---------- build xc = [att_ours, att_theirs, additional, h0[idx]] ----------
__global__ __launch_bounds__(256) void buildx_k(
    const float* __restrict__ att, const float* __restrict__ addl,
    const float* __restrict__ h0, const int* __restrict__ idx, float* __restrict__ xc){
  const int b = blockIdx.y;
  const int k = blockIdx.x * 256 + threadIdx.x;
  if (k >= 3328) return;
  float v;
  if (k < 1024)      v = att[(size_t)b * D_ + k];
  else if (k < 2048) v = att[(size_t)(32 + b) * D_ + (k - 1024)];
  else if (k < 2304) v = addl[b * ADD_ + (k - 2048)];
  else               v = h0[(size_t)idx[b] * H_ + (k - 2304)];
  xc[(size_t)b * 3328 + k] = v;
}

// ---------- LSTM pointwise: gates -> h,c; scatter to d_out; build next xc ----------
__global__ __launch_bounds__(256) void lstm_pw(
    const float* __restrict__ gates, const float* __restrict__ c_prev,
    const int* __restrict__ idx, float* __restrict__ h_out, float* __restrict__ c_out,
    float* __restrict__ xc_next, int xld, const float* __restrict__ gather_src){
  const int b = blockIdx.y;
  const int h = blockIdx.x * 256 + threadIdx.x;
  const int ib = idx[b];
  const float gi = gates[(size_t)b * 4096 + h];
  const float gf = gates[(size_t)b * 4096 + 1024 + h];
  const float gg = gates[(size_t)b * 4096 + 2048 + h];
  const float go = gates[(size_t)b * 4096 + 3072 + h];
  const float cp = c_prev[(size_t)ib * H_ + h];
  const float i = fast_sig(gi), f = fast_sig(gf), o = fast_sig(go);
  const float gt = fast_tanh(gg);
  const float cn = f * cp + i * gt;
  const float hn = o * fast_tanh(cn);
  h_out[(size_t)ib * H_ + h] = hn;
  c_out[(size_t)ib * H_ + h] = cn;
  xc_next[(size_t)b * xld + h] = hn;
  if (gather_src) xc_next[(size_t)b * xld + H_ + h] = gather_src[(size_t)ib * H_ + h];
}

extern "C" void kernel_launch(void* const* d_in, const int* in_sizes, int n_in,
                              void* d_out, int out_size, void* d_ws, size_t ws_size,
                              hipStream_t stream){
  const float* seq_ours   = (const float*)d_in[0];
  const int*   len_ours   = (const int*)d_in[1];
  const float* seq_theirs = (const float*)d_in[2];
  const int*   len_theirs = (const int*)d_in[3];
  const float* ctx        = (const float*)d_in[4];
  const float* addl       = (const float*)d_in[5];
  const float* h0 = (const float*)d_in[6];
  const float* c0 = (const float*)d_in[7];
  const float* h1 = (const float*)d_in[8];
  const float* c1 = (const float*)d_in[9];
  const int*   idx = (const int*)d_in[10];
  const float* Wh  = (const float*)d_in[11];
  const float* Wc  = (const float*)d_in[12];
  const float* v   = (const float*)d_in[13];
  const float* Wih0 = (const float*)d_in[14];
  const float* Whh0 = (const float*)d_in[15];
  const float* bih0 = (const float*)d_in[16];
  const float* bhh0 = (const float*)d_in[17];
  const float* Wih1 = (const float*)d_in[18];
  const float* Whh1 = (const float*)d_in[19];
  const float* bih1 = (const float*)d_in[20];
  const float* bhh1 = (const float*)d_in[21];
  const float* Wout = (const float*)d_in[22];
  const float* bout = (const float*)d_in[23];

  float* out = (float*)d_out;
  char* ws = (char*)d_ws;
  float*    ca     = (float*)(ws + 0);         // 32x1024
  float*    sraw   = (float*)(ws + 131072);    // 64x2048
  float*    p      = (float*)(ws + 655360);    // 64x2048
  float*    att    = (float*)(ws + 1179648);   // 64x1024
  float*    xc     = (float*)(ws + 1441792);   // 32x3328
  float*    gates0 = (float*)(ws + 1867776);   // 32x4096
  float*    xc1    = (float*)(ws + 2392064);   // 32x2048
  float*    gates1 = (float*)(ws + 2654208);   // 32x4096
  float*    xc2    = (float*)(ws + 3178496);   // 32x1024
  ushort_t* whbf   = (ushort_t*)(ws + 3309568);// 1024x1024 bf16

  hipMemsetAsync(sraw, 0, 64 * 2048 * 4, stream);
  hipMemsetAsync(att, 0, 64 * 1024 * 4, stream);
  copy4_k<<<512, 256, 0, stream>>>(h0, c0, h1, c1, out);
  cvt_wh_k<<<1024, 256, 0, stream>>>(Wh, whbf);
  gemm_small<<<128, 256, 0, stream>>>(ctx, 1024, Wc, 1024, nullptr, 0, nullptr, 0,
                                      nullptr, nullptr, ca, 1024, 1024, 0);
  score_gemm<<<dim3(8, 1024), 256, 0, stream>>>(seq_theirs, seq_ours, whbf, ca, v, sraw);
  softmax_k<<<64, 256, 0, stream>>>(sraw, len_theirs, len_ours, p, out);
  att_k<<<dim3(64, 16), 256, 0, stream>>>(seq_theirs, seq_ours, p, att);
  buildx_k<<<dim3(13, 32), 256, 0, stream>>>(att, addl, h0, idx, xc);
  gemm_small<<<512, 256, 0, stream>>>(xc, 3328, Wih0, 2304, xc + 2304, 3328, Whh0, 1024,
                                      bih0, bhh0, gates0, 4096, 4096, 0);
  lstm_pw<<<dim3(4, 32), 256, 0, stream>>>(gates0, c0, idx, out + 32768, out + 65536,
                                           xc1, 2048, h1);
  gemm_small<<<512, 256, 0, stream>>>(xc1, 2048, Wih1, 1024, xc1 + 1024, 2048, Whh1, 1024,
                                      bih1, bhh1, gates1, 4096, 4096, 0);
  lstm_pw<<<dim3(4, 32), 256, 0, stream>>>(gates1, c1, idx, out + 98304, out + 131072,
                                           xc2, 1024, nullptr);
  gemm_small<<<128, 256, 0, stream>>>(xc2, 1024, Wout, 1024, nullptr, 0, nullptr, 0,
                                      bout, nullptr, out, 1024, 1024, 1);
}

// Round 2
// 1221.146 us; speedup vs baseline: 1.1258x; 1.1258x over previous
//
#include <hip/hip_runtime.h>
#include <hip/hip_bf16.h>

typedef __bf16 bf16x8 __attribute__((ext_vector_type(8)));
typedef float  f32x16 __attribute__((ext_vector_type(16)));
typedef unsigned short ushort_t;

#define B_   32
#define S_   2048
#define D_   1024
#define A_   1024
#define ADD_ 256
#define H_   1024

// ---------- fast transcendentals ----------
__device__ __forceinline__ float fast_rcp(float x){ return __builtin_amdgcn_rcpf(x); }
__device__ __forceinline__ float fast_sig(float x){ return fast_rcp(1.f + __expf(-x)); }
__device__ __forceinline__ float fast_tanh(float x){
  float ax = fabsf(x);
  float e  = __expf(-2.f * ax);
  float t  = (1.f - e) * fast_rcp(1.f + e);
  return copysignf(t, x);
}
__device__ __forceinline__ unsigned bfbits(float x){
  return (unsigned)__builtin_bit_cast(ushort_t, (__bf16)x);
}

// async global->LDS 16B: builtin writes lds_base + lane*16 (wave-uniform base).
__device__ __forceinline__ void stage16(const void* g, uint4* lds_base, int lane){
#if __has_builtin(__builtin_amdgcn_global_load_lds)
  __builtin_amdgcn_global_load_lds((const __attribute__((address_space(1))) void*)g,
                                   (__attribute__((address_space(3))) void*)lds_base,
                                   16, 0, 0);
#else
  lds_base[lane] = *reinterpret_cast<const uint4*>(g);
#endif
}

// ---------- f32 -> bf16 vector convert (8 elems/thread) ----------
__global__ __launch_bounds__(256) void cvt8_k(const float* __restrict__ src,
                                              ushort_t* __restrict__ dst, int n8){
  int i = blockIdx.x * 256 + threadIdx.x;
  if (i >= n8) return;
  float4 a = reinterpret_cast<const float4*>(src)[i * 2];
  float4 b = reinterpret_cast<const float4*>(src)[i * 2 + 1];
  uint4 o;
  o.x = bfbits(a.x) | (bfbits(a.y) << 16);
  o.y = bfbits(a.z) | (bfbits(a.w) << 16);
  o.z = bfbits(b.x) | (bfbits(b.y) << 16);
  o.w = bfbits(b.z) | (bfbits(b.w) << 16);
  reinterpret_cast<uint4*>(dst)[i] = o;
}

// ---------- fused score GEMM: sraw[g][s] += sum_a tanh(hist·Wh^T + ca)·v ----------
// BM=128 x BN=128 x BK=64; 4 waves (2x2), wave tile 64x64 via 2x2 frags of
// v_mfma_f32_32x32x16_bf16 (round-1 verified layout). LDS rows of 8 x 16B slots,
// phys_slot = logical_slot ^ (row&7).
// PRECVT=true: A staged from pre-converted bf16 via global_load_lds (linear LDS
// dest + inverse-swizzled global source). PRECVT=false: round-1 fused f32->bf16.
template<bool PRECVT>
__global__ __launch_bounds__(256) void score_gemm(
    const float* __restrict__ hist_theirs, const float* __restrict__ hist_ours,
    const ushort_t* __restrict__ bfA, const ushort_t* __restrict__ whbf,
    const float* __restrict__ ca, const float* __restrict__ vvec,
    float* __restrict__ sraw){
  __shared__ uint4 As4[1024];   // 128 rows x 8 slots
  __shared__ uint4 Bs4[1024];

  const int t  = threadIdx.x;
  const int bx = blockIdx.x;            // 0..7  col tile
  const int by = blockIdx.y;            // 0..1023 row tile (bx fastest -> co-readers time-local)
  const int g  = by >> 4;
  const int b  = g & 31;
  const int srow0 = (by & 15) * 128;

  const int w = t >> 6, lane = t & 63;
  const int wr = w >> 1, wc = w & 1;
  const int l31 = lane & 31, lhi = lane >> 5;

  // linear-staging slot math: L = it*256 + t ; row = L>>3 ; s = (L&7)^(row&7)
  int Lrow[4], Ls[4];
  #pragma unroll
  for (int it = 0; it < 4; it++){
    int L = it * 256 + t;
    Lrow[it] = L >> 3;
    Ls[it]   = (L & 7) ^ ((L >> 3) & 7);
  }
  const ushort_t* bsrc[4];
  #pragma unroll
  for (int it = 0; it < 4; it++)
    bsrc[it] = whbf + (size_t)(bx * 128 + Lrow[it]) * D_ + Ls[it] * 8;

  const ushort_t* asrcb[4];
  const float* asrcf = nullptr; int sr = 0, sh = 0;
  if (PRECVT){
    #pragma unroll
    for (int it = 0; it < 4; it++)
      asrcb[it] = bfA + ((size_t)g * S_ + srow0 + Lrow[it]) * D_ + Ls[it] * 8;
  } else {
    sr = t >> 1; sh = t & 1;
    asrcf = ((g < 32) ? hist_theirs : hist_ours)
            + (size_t)b * S_ * D_ + (size_t)(srow0 + sr) * D_ + sh * 32;
  }

  f32x16 acc[2][2];
  #pragma unroll
  for (int m = 0; m < 2; m++)
    #pragma unroll
    for (int n = 0; n < 2; n++)
      #pragma unroll
      for (int i = 0; i < 16; i++) acc[m][n][i] = 0.f;

  for (int kc = 0; kc < D_; kc += 64) {
    if (PRECVT){
      #pragma unroll
      for (int it = 0; it < 4; it++)
        stage16(asrcb[it] + kc, &As4[it * 256 + w * 64], lane);
    } else {
      const float* p = asrcf + kc;
      float4 f[8];
      #pragma unroll
      for (int i = 0; i < 8; i++) f[i] = *reinterpret_cast<const float4*>(p + i * 4);
      #pragma unroll
      for (int j = 0; j < 4; j++) {
        bf16x8 o;
        float4 u = f[2 * j], v2 = f[2 * j + 1];
        o[0] = (__bf16)u.x;  o[1] = (__bf16)u.y;  o[2] = (__bf16)u.z;  o[3] = (__bf16)u.w;
        o[4] = (__bf16)v2.x; o[5] = (__bf16)v2.y; o[6] = (__bf16)v2.z; o[7] = (__bf16)v2.w;
        *reinterpret_cast<bf16x8*>(&As4[sr * 8 + ((sh * 4 + j) ^ (sr & 7))]) = o;
      }
    }
    #pragma unroll
    for (int it = 0; it < 4; it++)
      stage16(bsrc[it] + kc, &Bs4[it * 256 + w * 64], lane);
    __syncthreads();   // drains vmcnt(0)+lgkmcnt(0) then barrier

    #pragma unroll
    for (int ks = 0; ks < 4; ks++) {
      bf16x8 af[2], bfr[2];
      #pragma unroll
      for (int m = 0; m < 2; m++) {
        int ar = wr * 64 + m * 32 + l31;
        af[m] = *reinterpret_cast<const bf16x8*>(&As4[ar * 8 + ((ks * 2 + lhi) ^ (ar & 7))]);
      }
      #pragma unroll
      for (int n = 0; n < 2; n++) {
        int br = wc * 64 + n * 32 + l31;
        bfr[n] = *reinterpret_cast<const bf16x8*>(&Bs4[br * 8 + ((ks * 2 + lhi) ^ (br & 7))]);
      }
      #pragma unroll
      for (int m = 0; m < 2; m++)
        #pragma unroll
        for (int n = 0; n < 2; n++)
          acc[m][n] = __builtin_amdgcn_mfma_f32_32x32x16_bf16(af[m], bfr[n], acc[m][n], 0, 0, 0);
    }
    __syncthreads();
  }

  // epilogue: tanh(ha+ca)*v, reduce over 128 block cols, atomicAdd partials
  float cav[2], vv[2];
  #pragma unroll
  for (int n = 0; n < 2; n++) {
    int col = bx * 128 + wc * 64 + n * 32 + l31;
    cav[n] = ca[b * A_ + col];
    vv[n]  = vvec[col];
  }
  #pragma unroll
  for (int m = 0; m < 2; m++) {
    float ts[16];
    #pragma unroll
    for (int r = 0; r < 16; r++) ts[r] = 0.f;
    #pragma unroll
    for (int n = 0; n < 2; n++)
      #pragma unroll
      for (int r = 0; r < 16; r++)
        ts[r] += fast_tanh(acc[m][n][r] + cav[n]) * vv[n];
    #pragma unroll
    for (int off = 1; off < 32; off <<= 1)
      #pragma unroll
      for (int r = 0; r < 16; r++)
        ts[r] += __shfl_xor(ts[r], off, 64);
    if (l31 == 0) {
      int rb = srow0 + wr * 64 + m * 32 + lhi * 4;
      #pragma unroll
      for (int r = 0; r < 16; r++) {
        int row = rb + (r & 3) + 8 * (r >> 2);
        atomicAdd(&sraw[(size_t)g * S_ + row], ts[r]);
      }
    }
  }
}

// ---------- masked softmax over S per g ----------
__global__ __launch_bounds__(256) void softmax_k(
    const float* __restrict__ sraw, const int* __restrict__ len_theirs,
    const int* __restrict__ len_ours, float* __restrict__ p, float* __restrict__ dout){
  const int g = blockIdx.x, t = threadIdx.x;
  const int len = (g < 32) ? len_theirs[g] : len_ours[g - 32];
  const float* row = sraw + (size_t)g * S_;
  float vals[8];
  #pragma unroll
  for (int i = 0; i < 8; i++) vals[i] = row[t * 8 + i];
  float mx = -1e30f;
  #pragma unroll
  for (int i = 0; i < 8; i++) if (t * 8 + i < len) mx = fmaxf(mx, vals[i]);
  #pragma unroll
  for (int off = 1; off < 64; off <<= 1) mx = fmaxf(mx, __shfl_xor(mx, off, 64));
  __shared__ float redm[4], reds[4];
  if ((t & 63) == 0) redm[t >> 6] = mx;
  __syncthreads();
  mx = fmaxf(fmaxf(redm[0], redm[1]), fmaxf(redm[2], redm[3]));
  float e[8]; float sum = 0.f;
  #pragma unroll
  for (int i = 0; i < 8; i++) {
    int s = t * 8 + i;
    e[i] = (s < len) ? __expf(vals[i] - mx) : 0.f;
    sum += e[i];
  }
  #pragma unroll
  for (int off = 1; off < 64; off <<= 1) sum += __shfl_xor(sum, off, 64);
  if ((t & 63) == 0) reds[t >> 6] = sum;
  __syncthreads();
  sum = reds[0] + reds[1] + reds[2] + reds[3];
  float rs = fast_rcp(sum);
  float* pd = p + (size_t)g * S_;
  float* od = (g < 32) ? (dout + 163840 + (size_t)g * S_)
                       : (dout + 229376 + (size_t)(g - 32) * S_);
  #pragma unroll
  for (int i = 0; i < 8; i++) {
    float pv = e[i] * rs;
    pd[t * 8 + i] = pv;
    od[t * 8 + i] = pv;
  }
}

// ---------- att[g][d] = sum_s p[g,s]*hist[g,s,d]  (HBM-bound) ----------
__global__ __launch_bounds__(256) void att_k(
    const float* __restrict__ hist_theirs, const float* __restrict__ hist_ours,
    const float* __restrict__ p, float* __restrict__ att){
  const int g = blockIdx.x, ch = blockIdx.y, t = threadIdx.x;
  const float* hist = (g < 32 ? hist_theirs : hist_ours) + (size_t)(g & 31) * S_ * D_;
  const int s0 = ch * 128;
  __shared__ float ps[128];
  if (t < 128) ps[t] = p[(size_t)g * S_ + s0 + t];
  __syncthreads();
  float ax = 0.f, ay = 0.f, az = 0.f, aw = 0.f;
  const float* hp = hist + (size_t)s0 * D_ + t * 4;
  #pragma unroll 8
  for (int i = 0; i < 128; i++) {
    float4 hv = *reinterpret_cast<const float4*>(hp + (size_t)i * D_);
    float wgt = ps[i];
    ax += wgt * hv.x; ay += wgt * hv.y; az += wgt * hv.z; aw += wgt * hv.w;
  }
  float* ad = att + (size_t)g * D_ + t * 4;
  atomicAdd(ad + 0, ax); atomicAdd(ad + 1, ay);
  atomicAdd(ad + 2, az); atomicAdd(ad + 3, aw);
}

// ---------- generic small-M GEMM: out[b][j] = act( X·W^T + bias ), M=32 ----------
__global__ __launch_bounds__(256) void gemm_small(
    const float* __restrict__ X1, int ldx1, const float* __restrict__ W1, int K1,
    const float* __restrict__ X2, int ldx2, const float* __restrict__ W2, int K2,
    const float* __restrict__ b1, const float* __restrict__ b2,
    float* __restrict__ out, int ldo, int N, int act){
  const int lane = threadIdx.x & 63;
  const int wv   = blockIdx.x * 4 + (threadIdx.x >> 6);
  const int j0   = wv * 2;
  if (j0 >= N) return;
  float acc0[32], acc1[32];
  #pragma unroll
  for (int i = 0; i < 32; i++) { acc0[i] = 0.f; acc1[i] = 0.f; }
  {
    const float* w0p = W1 + (size_t)j0 * K1;
    const float* w1p = W1 + (size_t)(j0 + 1) * K1;
    for (int kc = lane * 4; kc < K1; kc += 256) {
      float4 w0 = *reinterpret_cast<const float4*>(w0p + kc);
      float4 w1 = *reinterpret_cast<const float4*>(w1p + kc);
      #pragma unroll
      for (int bb = 0; bb < 32; bb++) {
        float4 xv = *reinterpret_cast<const float4*>(X1 + (size_t)bb * ldx1 + kc);
        acc0[bb] += w0.x * xv.x + w0.y * xv.y + w0.z * xv.z + w0.w * xv.w;
        acc1[bb] += w1.x * xv.x + w1.y * xv.y + w1.z * xv.z + w1.w * xv.w;
      }
    }
  }
  if (W2) {
    const float* w0p = W2 + (size_t)j0 * K2;
    const float* w1p = W2 + (size_t)(j0 + 1) * K2;
    for (int kc = lane * 4; kc < K2; kc += 256) {
      float4 w0 = *reinterpret_cast<const float4*>(w0p + kc);
      float4 w1 = *reinterpret_cast<const float4*>(w1p + kc);
      #pragma unroll
      for (int bb = 0; bb < 32; bb++) {
        float4 xv = *reinterpret_cast<const float4*>(X2 + (size_t)bb * ldx2 + kc);
        acc0[bb] += w0.x * xv.x + w0.y * xv.y + w0.z * xv.z + w0.w * xv.w;
        acc1[bb] += w1.x * xv.x + w1.y * xv.y + w1.z * xv.z + w1.w * xv.w;
      }
    }
  }
  #pragma unroll
  for (int off = 1; off < 64; off <<= 1)
    #pragma unroll
    for (int bb = 0; bb < 32; bb++) {
      acc0[bb] += __shfl_xor(acc0[bb], off, 64);
      acc1[bb] += __shfl_xor(acc1[bb], off, 64);
    }
  float r0 = 0.f, r1 = 0.f;
  #pragma unroll
  for (int bb = 0; bb < 32; bb++) {
    if ((lane & 31) == bb) { r0 = acc0[bb]; r1 = acc1[bb]; }
  }
  if (lane < 32) {
    float bias0 = (b1 ? b1[j0] : 0.f) + (b2 ? b2[j0] : 0.f);
    float bias1 = (b1 ? b1[j0 + 1] : 0.f) + (b2 ? b2[j0 + 1] : 0.f);
    float v0 = r0 + bias0, v1 = r1 + bias1;
    if (act == 1) { v0 = fast_tanh(v0); v1 = fast_tanh(v1); }
    out[(size_t)lane * ldo + j0]     = v0;
    out[(size_t)lane * ldo + j0 + 1] = v1;
  }
}

// ---------- build xc = [att_ours, att_theirs, additional, h0[idx]] ----------
__global__ __launch_bounds__(256) void buildx_k(
    const float* __restrict__ att, const float* __restrict__ addl,
    const float* __restrict__ h0, const int* __restrict__ idx, float* __restrict__ xc){
  const int b = blockIdx.y;
  const int k = blockIdx.x * 256 + threadIdx.x;
  if (k >= 3328) return;
  float v;
  if (k < 1024)      v = att[(size_t)b * D_ + k];
  else if (k < 2048) v = att[(size_t)(32 + b) * D_ + (k - 1024)];
  else if (k < 2304) v = addl[b * ADD_ + (k - 2048)];
  else               v = h0[(size_t)idx[b] * H_ + (k - 2304)];
  xc[(size_t)b * 3328 + k] = v;
}

// ---------- LSTM pointwise ----------
__global__ __launch_bounds__(256) void lstm_pw(
    const float* __restrict__ gates, const float* __restrict__ c_prev,
    const int* __restrict__ idx, float* __restrict__ h_out, float* __restrict__ c_out,
    float* __restrict__ xc_next, int xld, const float* __restrict__ gather_src){
  const int b = blockIdx.y;
  const int h = blockIdx.x * 256 + threadIdx.x;
  const int ib = idx[b];
  const float gi = gates[(size_t)b * 4096 + h];
  const float gf = gates[(size_t)b * 4096 + 1024 + h];
  const float gg = gates[(size_t)b * 4096 + 2048 + h];
  const float go = gates[(size_t)b * 4096 + 3072 + h];
  const float cp = c_prev[(size_t)ib * H_ + h];
  const float i = fast_sig(gi), f = fast_sig(gf), o = fast_sig(go);
  const float gt = fast_tanh(gg);
  const float cn = f * cp + i * gt;
  const float hn = o * fast_tanh(cn);
  h_out[(size_t)ib * H_ + h] = hn;
  c_out[(size_t)ib * H_ + h] = cn;
  xc_next[(size_t)b * xld + h] = hn;
  if (gather_src) xc_next[(size_t)b * xld + H_ + h] = gather_src[(size_t)ib * H_ + h];
}

extern "C" void kernel_launch(void* const* d_in, const int* in_sizes, int n_in,
                              void* d_out, int out_size, void* d_ws, size_t ws_size,
                              hipStream_t stream){
  const float* seq_ours   = (const float*)d_in[0];
  const int*   len_ours   = (const int*)d_in[1];
  const float* seq_theirs = (const float*)d_in[2];
  const int*   len_theirs = (const int*)d_in[3];
  const float* ctx        = (const float*)d_in[4];
  const float* addl       = (const float*)d_in[5];
  const float* h0 = (const float*)d_in[6];
  const float* c0 = (const float*)d_in[7];
  const float* h1 = (const float*)d_in[8];
  const float* c1 = (const float*)d_in[9];
  const int*   idx = (const int*)d_in[10];
  const float* Wh  = (const float*)d_in[11];
  const float* Wc  = (const float*)d_in[12];
  const float* v   = (const float*)d_in[13];
  const float* Wih0 = (const float*)d_in[14];
  const float* Whh0 = (const float*)d_in[15];
  const float* bih0 = (const float*)d_in[16];
  const float* bhh0 = (const float*)d_in[17];
  const float* Wih1 = (const float*)d_in[18];
  const float* Whh1 = (const float*)d_in[19];
  const float* bih1 = (const float*)d_in[20];
  const float* bhh1 = (const float*)d_in[21];
  const float* Wout = (const float*)d_in[22];
  const float* bout = (const float*)d_in[23];

  float* out = (float*)d_out;
  char* ws = (char*)d_ws;
  float*    ca     = (float*)(ws + 0);         // 32x1024
  float*    sraw   = (float*)(ws + 131072);    // 64x2048
  float*    p      = (float*)(ws + 655360);    // 64x2048
  float*    att    = (float*)(ws + 1179648);   // 64x1024
  float*    xc     = (float*)(ws + 1441792);   // 32x3328
  float*    gates0 = (float*)(ws + 1867776);   // 32x4096
  float*    xc1    = (float*)(ws + 2392064);   // 32x2048
  float*    gates1 = (float*)(ws + 2654208);   // 32x4096
  float*    xc2    = (float*)(ws + 3178496);   // 32x1024
  ushort_t* whbf   = (ushort_t*)(ws + 3309568);// 1024x1024 bf16
  ushort_t* bfA    = (ushort_t*)(ws + 5406720);// 2x32x2048x1024 bf16 (268435456 B)

  const size_t NEED = 5406720ull + 268435456ull;
  const bool precvt = ws_size >= NEED;

  hipMemsetAsync(sraw, 0, 64 * 2048 * 4, stream);
  hipMemsetAsync(att, 0, 64 * 1024 * 4, stream);
  cvt8_k<<<512, 256, 0, stream>>>(Wh, whbf, 131072);
  if (precvt){
    cvt8_k<<<32768, 256, 0, stream>>>(seq_theirs, bfA,            8388608);
    cvt8_k<<<32768, 256, 0, stream>>>(seq_ours,   bfA + 67108864, 8388608);
  }
  gemm_small<<<128, 256, 0, stream>>>(ctx, 1024, Wc, 1024, nullptr, 0, nullptr, 0,
                                      nullptr, nullptr, ca, 1024, 1024, 0);
  if (precvt)
    score_gemm<true><<<dim3(8, 1024), 256, 0, stream>>>(
        seq_theirs, seq_ours, bfA, whbf, ca, v, sraw);
  else
    score_gemm<false><<<dim3(8, 1024), 256, 0, stream>>>(
        seq_theirs, seq_ours, bfA, whbf, ca, v, sraw);
  softmax_k<<<64, 256, 0, stream>>>(sraw, len_theirs, len_ours, p, out);
  att_k<<<dim3(64, 16), 256, 0, stream>>>(seq_theirs, seq_ours, p, att);
  buildx_k<<<dim3(13, 32), 256, 0, stream>>>(att, addl, h0, idx, xc);
  gemm_small<<<512, 256, 0, stream>>>(xc, 3328, Wih0, 2304, xc + 2304, 3328, Whh0, 1024,
                                      bih0, bhh0, gates0, 4096, 4096, 0);
  lstm_pw<<<dim3(4, 32), 256, 0, stream>>>(gates0, c0, idx, out + 32768, out + 65536,
                                           xc1, 2048, h1);
  gemm_small<<<512, 256, 0, stream>>>(xc1, 2048, Wih1, 1024, xc1 + 1024, 2048, Whh1, 1024,
                                      bih1, bhh1, gates1, 4096, 4096, 0);
  lstm_pw<<<dim3(4, 32), 256, 0, stream>>>(gates1, c1, idx, out + 98304, out + 131072,
                                           xc2, 1024, nullptr);
  gemm_small<<<128, 256, 0, stream>>>(xc2, 1024, Wout, 1024, nullptr, 0, nullptr, 0,
                                      bout, nullptr, out, 1024, 1024, 1);
}

// Round 9
// 1126.197 us; speedup vs baseline: 1.2207x; 1.0843x over previous
//
#include <hip/hip_runtime.h>
#include <hip/hip_bf16.h>

typedef __bf16 bf16x8 __attribute__((ext_vector_type(8)));
typedef float  f32x16 __attribute__((ext_vector_type(16)));
typedef unsigned short ushort_t;

#define B_   32
#define S_   2048
#define D_   1024
#define A_   1024
#define ADD_ 256
#define H_   1024

// ---------- fast transcendentals ----------
__device__ __forceinline__ float fast_rcp(float x){ return __builtin_amdgcn_rcpf(x); }
__device__ __forceinline__ float fast_sig(float x){ return fast_rcp(1.f + __expf(-x)); }
__device__ __forceinline__ float fast_tanh(float x){
  float ax = fabsf(x);
  float e  = __expf(-2.f * ax);
  float t  = (1.f - e) * fast_rcp(1.f + e);
  return copysignf(t, x);
}
__device__ __forceinline__ unsigned bfbits(float x){
  return (unsigned)__builtin_bit_cast(ushort_t, (__bf16)x);
}
__device__ __forceinline__ float bf_lo(unsigned u){ return __builtin_bit_cast(float, u << 16); }
__device__ __forceinline__ float bf_hi(unsigned u){ return __builtin_bit_cast(float, u & 0xffff0000u); }

// async global->LDS 16B: builtin writes lds_base + lane*16 (wave-uniform base).
__device__ __forceinline__ void stage16(const void* g, uint4* lds_base, int lane){
#if __has_builtin(__builtin_amdgcn_global_load_lds)
  __builtin_amdgcn_global_load_lds((const __attribute__((address_space(1))) void*)g,
                                   (__attribute__((address_space(3))) void*)lds_base,
                                   16, 0, 0);
#else
  lds_base[lane] = *reinterpret_cast<const uint4*>(g);
#endif
}

// ---------- f32 -> bf16 vector convert (16 elems/thread) ----------
__global__ __launch_bounds__(256) void cvt16_k(const float* __restrict__ src,
                                               ushort_t* __restrict__ dst, int n16){
  int i = blockIdx.x * 256 + threadIdx.x;
  if (i >= n16) return;
  const float4* s4 = reinterpret_cast<const float4*>(src) + (size_t)i * 4;
  float4 a = s4[0], b = s4[1], c = s4[2], d = s4[3];
  uint4 o0, o1;
  o0.x = bfbits(a.x) | (bfbits(a.y) << 16);
  o0.y = bfbits(a.z) | (bfbits(a.w) << 16);
  o0.z = bfbits(b.x) | (bfbits(b.y) << 16);
  o0.w = bfbits(b.z) | (bfbits(b.w) << 16);
  o1.x = bfbits(c.x) | (bfbits(c.y) << 16);
  o1.y = bfbits(c.z) | (bfbits(c.w) << 16);
  o1.z = bfbits(d.x) | (bfbits(d.y) << 16);
  o1.w = bfbits(d.z) | (bfbits(d.w) << 16);
  uint4* dp = reinterpret_cast<uint4*>(dst) + (size_t)i * 2;
  dp[0] = o0; dp[1] = o1;
}

// ---------- fused score GEMM: sraw[g][s] += sum_a tanh(hist·Wh^T + ca)·v ----------
// BM=128 x BN=128 x BK=64; 4 waves (2x2), wave tile 64x64 via 2x2 frags of
// v_mfma_f32_32x32x16_bf16 (verified layout). LDS rows of 8 x 16B slots,
// phys_slot = logical_slot ^ (row&7).
// Flat 8192-block grid with XCD-bijective swizzle: the 8 col-tile co-readers of
// each A row-tile get block ids differing by 8 (same XCD under round-robin,
// within a 64-id dispatch window) -> A tile becomes an XCD-L2 hit.
template<bool PRECVT>
__global__ __launch_bounds__(256) void score_gemm(
    const float* __restrict__ hist_theirs, const float* __restrict__ hist_ours,
    const ushort_t* __restrict__ bfA, const ushort_t* __restrict__ whbf,
    const float* __restrict__ ca, const float* __restrict__ vvec,
    float* __restrict__ sraw){
  __shared__ uint4 As4[1024];   // 128 rows x 8 slots
  __shared__ uint4 Bs4[1024];

  const int t   = threadIdx.x;
  const int bid = blockIdx.x;                 // 0..8191
  const int bx  = (bid >> 3) & 7;             // col tile
  const int by  = ((bid >> 6) << 3) | (bid & 7);  // row tile (bijective)
  const int g  = by >> 4;
  const int b  = g & 31;
  const int srow0 = (by & 15) * 128;

  const int w = t >> 6, lane = t & 63;
  const int wr = w >> 1, wc = w & 1;
  const int l31 = lane & 31, lhi = lane >> 5;

  // linear-staging slot math: L = it*256 + t ; row = L>>3 ; s = (L&7)^(row&7)
  int Lrow[4], Ls[4];
  #pragma unroll
  for (int it = 0; it < 4; it++){
    int L = it * 256 + t;
    Lrow[it] = L >> 3;
    Ls[it]   = (L & 7) ^ ((L >> 3) & 7);
  }
  const ushort_t* bsrc[4];
  #pragma unroll
  for (int it = 0; it < 4; it++)
    bsrc[it] = whbf + (size_t)(bx * 128 + Lrow[it]) * D_ + Ls[it] * 8;

  const ushort_t* asrcb[4];
  const float* asrcf = nullptr; int sr = 0, sh = 0;
  if (PRECVT){
    #pragma unroll
    for (int it = 0; it < 4; it++)
      asrcb[it] = bfA + ((size_t)g * S_ + srow0 + Lrow[it]) * D_ + Ls[it] * 8;
  } else {
    sr = t >> 1; sh = t & 1;
    asrcf = ((g < 32) ? hist_theirs : hist_ours)
            + (size_t)b * S_ * D_ + (size_t)(srow0 + sr) * D_ + sh * 32;
  }

  f32x16 acc[2][2];
  #pragma unroll
  for (int m = 0; m < 2; m++)
    #pragma unroll
    for (int n = 0; n < 2; n++)
      #pragma unroll
      for (int i = 0; i < 16; i++) acc[m][n][i] = 0.f;

  for (int kc = 0; kc < D_; kc += 64) {
    if (PRECVT){
      #pragma unroll
      for (int it = 0; it < 4; it++)
        stage16(asrcb[it] + kc, &As4[it * 256 + w * 64], lane);
    } else {
      const float* p = asrcf + kc;
      float4 f[8];
      #pragma unroll
      for (int i = 0; i < 8; i++) f[i] = *reinterpret_cast<const float4*>(p + i * 4);
      #pragma unroll
      for (int j = 0; j < 4; j++) {
        bf16x8 o;
        float4 u = f[2 * j], v2 = f[2 * j + 1];
        o[0] = (__bf16)u.x;  o[1] = (__bf16)u.y;  o[2] = (__bf16)u.z;  o[3] = (__bf16)u.w;
        o[4] = (__bf16)v2.x; o[5] = (__bf16)v2.y; o[6] = (__bf16)v2.z; o[7] = (__bf16)v2.w;
        *reinterpret_cast<bf16x8*>(&As4[sr * 8 + ((sh * 4 + j) ^ (sr & 7))]) = o;
      }
    }
    #pragma unroll
    for (int it = 0; it < 4; it++)
      stage16(bsrc[it] + kc, &Bs4[it * 256 + w * 64], lane);
    __syncthreads();   // drains vmcnt(0)+lgkmcnt(0) then barrier

    #pragma unroll
    for (int ks = 0; ks < 4; ks++) {
      bf16x8 af[2], bfr[2];
      #pragma unroll
      for (int m = 0; m < 2; m++) {
        int ar = wr * 64 + m * 32 + l31;
        af[m] = *reinterpret_cast<const bf16x8*>(&As4[ar * 8 + ((ks * 2 + lhi) ^ (ar & 7))]);
      }
      #pragma unroll
      for (int n = 0; n < 2; n++) {
        int br = wc * 64 + n * 32 + l31;
        bfr[n] = *reinterpret_cast<const bf16x8*>(&Bs4[br * 8 + ((ks * 2 + lhi) ^ (br & 7))]);
      }
      #pragma unroll
      for (int m = 0; m < 2; m++)
        #pragma unroll
        for (int n = 0; n < 2; n++)
          acc[m][n] = __builtin_amdgcn_mfma_f32_32x32x16_bf16(af[m], bfr[n], acc[m][n], 0, 0, 0);
    }
    __syncthreads();
  }

  // epilogue: tanh(ha+ca)*v, reduce over 128 block cols, atomicAdd partials
  float cav[2], vv[2];
  #pragma unroll
  for (int n = 0; n < 2; n++) {
    int col = bx * 128 + wc * 64 + n * 32 + l31;
    cav[n] = ca[b * A_ + col];
    vv[n]  = vvec[col];
  }
  #pragma unroll
  for (int m = 0; m < 2; m++) {
    float ts[16];
    #pragma unroll
    for (int r = 0; r < 16; r++) ts[r] = 0.f;
    #pragma unroll
    for (int n = 0; n < 2; n++)
      #pragma unroll
      for (int r = 0; r < 16; r++)
        ts[r] += fast_tanh(acc[m][n][r] + cav[n]) * vv[n];
    #pragma unroll
    for (int off = 1; off < 32; off <<= 1)
      #pragma unroll
      for (int r = 0; r < 16; r++)
        ts[r] += __shfl_xor(ts[r], off, 64);
    if (l31 == 0) {
      int rb = srow0 + wr * 64 + m * 32 + lhi * 4;
      #pragma unroll
      for (int r = 0; r < 16; r++) {
        int row = rb + (r & 3) + 8 * (r >> 2);
        atomicAdd(&sraw[(size_t)g * S_ + row], ts[r]);
      }
    }
  }
}

// ---------- masked softmax over S per g ----------
__global__ __launch_bounds__(256) void softmax_k(
    const float* __restrict__ sraw, const int* __restrict__ len_theirs,
    const int* __restrict__ len_ours, float* __restrict__ p, float* __restrict__ dout){
  const int g = blockIdx.x, t = threadIdx.x;
  const int len = (g < 32) ? len_theirs[g] : len_ours[g - 32];
  const float* row = sraw + (size_t)g * S_;
  float vals[8];
  #pragma unroll
  for (int i = 0; i < 8; i++) vals[i] = row[t * 8 + i];
  float mx = -1e30f;
  #pragma unroll
  for (int i = 0; i < 8; i++) if (t * 8 + i < len) mx = fmaxf(mx, vals[i]);
  #pragma unroll
  for (int off = 1; off < 64; off <<= 1) mx = fmaxf(mx, __shfl_xor(mx, off, 64));
  __shared__ float redm[4], reds[4];
  if ((t & 63) == 0) redm[t >> 6] = mx;
  __syncthreads();
  mx = fmaxf(fmaxf(redm[0], redm[1]), fmaxf(redm[2], redm[3]));
  float e[8]; float sum = 0.f;
  #pragma unroll
  for (int i = 0; i < 8; i++) {
    int s = t * 8 + i;
    e[i] = (s < len) ? __expf(vals[i] - mx) : 0.f;
    sum += e[i];
  }
  #pragma unroll
  for (int off = 1; off < 64; off <<= 1) sum += __shfl_xor(sum, off, 64);
  if ((t & 63) == 0) reds[t >> 6] = sum;
  __syncthreads();
  sum = reds[0] + reds[1] + reds[2] + reds[3];
  float rs = fast_rcp(sum);
  float* pd = p + (size_t)g * S_;
  float* od = (g < 32) ? (dout + 163840 + (size_t)g * S_)
                       : (dout + 229376 + (size_t)(g - 32) * S_);
  #pragma unroll
  for (int i = 0; i < 8; i++) {
    float pv = e[i] * rs;
    pd[t * 8 + i] = pv;
    od[t * 8 + i] = pv;
  }
}

// ---------- att partials: att_part[ch][g][d] = sum_{s in chunk} p[g,s]*hist[g,s,d] ----------
// No atomics: 8 s-chunks of 256 rows write disjoint partial buffers (combined in buildx).
template<bool PRECVT>
__global__ __launch_bounds__(256) void att_k(
    const float* __restrict__ hist_theirs, const float* __restrict__ hist_ours,
    const ushort_t* __restrict__ bfA, const float* __restrict__ p,
    float* __restrict__ att_part){
  const int g = blockIdx.x, ch = blockIdx.y, t = threadIdx.x;
  const int s0 = ch * 256;
  __shared__ float ps[256];
  ps[t] = p[(size_t)g * S_ + s0 + t];
  __syncthreads();
  float* op = att_part + ((size_t)ch * 64 + g) * D_;
  if (PRECVT){
    __shared__ float red[128 * 8];
    const int d0 = (t & 127) * 8;
    const int sh = t >> 7;
    const ushort_t* hp = bfA + ((size_t)g * S_ + s0 + sh * 128) * D_ + d0;
    float acc[8];
    #pragma unroll
    for (int j = 0; j < 8; j++) acc[j] = 0.f;
    #pragma unroll 4
    for (int i = 0; i < 128; i++){
      uint4 u = *reinterpret_cast<const uint4*>(hp + (size_t)i * D_);
      float wgt = ps[sh * 128 + i];
      acc[0] += wgt * bf_lo(u.x); acc[1] += wgt * bf_hi(u.x);
      acc[2] += wgt * bf_lo(u.y); acc[3] += wgt * bf_hi(u.y);
      acc[4] += wgt * bf_lo(u.z); acc[5] += wgt * bf_hi(u.z);
      acc[6] += wgt * bf_lo(u.w); acc[7] += wgt * bf_hi(u.w);
    }
    if (sh == 1){
      #pragma unroll
      for (int j = 0; j < 8; j++) red[(t - 128) * 8 + j] = acc[j];
    }
    __syncthreads();
    if (sh == 0){
      #pragma unroll
      for (int j = 0; j < 8; j++) op[d0 + j] = acc[j] + red[t * 8 + j];
    }
  } else {
    const int d0 = t * 4;
    const float* hist = (g < 32 ? hist_theirs : hist_ours) + (size_t)(g & 31) * S_ * D_;
    const float* hp = hist + (size_t)s0 * D_ + d0;
    float ax = 0.f, ay = 0.f, az = 0.f, aw = 0.f;
    #pragma unroll 4
    for (int i = 0; i < 256; i++){
      float4 hv = *reinterpret_cast<const float4*>(hp + (size_t)i * D_);
      float wgt = ps[i];
      ax += wgt * hv.x; ay += wgt * hv.y; az += wgt * hv.z; aw += wgt * hv.w;
    }
    op[d0] = ax; op[d0 + 1] = ay; op[d0 + 2] = az; op[d0 + 3] = aw;
  }
}

// ---------- generic small-M GEMM: out[b][j] = act( X·W^T + bias ), M=32 ----------
__global__ __launch_bounds__(256) void gemm_small(
    const float* __restrict__ X1, int ldx1, const float* __restrict__ W1, int K1,
    const float* __restrict__ X2, int ldx2, const float* __restrict__ W2, int K2,
    const float* __restrict__ b1, const float* __restrict__ b2,
    float* __restrict__ out, int ldo, int N, int act){
  const int lane = threadIdx.x & 63;
  const int wv   = blockIdx.x * 4 + (threadIdx.x >> 6);
  const int j0   = wv * 2;
  if (j0 >= N) return;
  float acc0[32], acc1[32];
  #pragma unroll
  for (int i = 0; i < 32; i++) { acc0[i] = 0.f; acc1[i] = 0.f; }
  {
    const float* w0p = W1 + (size_t)j0 * K1;
    const float* w1p = W1 + (size_t)(j0 + 1) * K1;
    for (int kc = lane * 4; kc < K1; kc += 256) {
      float4 w0 = *reinterpret_cast<const float4*>(w0p + kc);
      float4 w1 = *reinterpret_cast<const float4*>(w1p + kc);
      #pragma unroll
      for (int bb = 0; bb < 32; bb++) {
        float4 xv = *reinterpret_cast<const float4*>(X1 + (size_t)bb * ldx1 + kc);
        acc0[bb] += w0.x * xv.x + w0.y * xv.y + w0.z * xv.z + w0.w * xv.w;
        acc1[bb] += w1.x * xv.x + w1.y * xv.y + w1.z * xv.z + w1.w * xv.w;
      }
    }
  }
  if (W2) {
    const float* w0p = W2 + (size_t)j0 * K2;
    const float* w1p = W2 + (size_t)(j0 + 1) * K2;
    for (int kc = lane * 4; kc < K2; kc += 256) {
      float4 w0 = *reinterpret_cast<const float4*>(w0p + kc);
      float4 w1 = *reinterpret_cast<const float4*>(w1p + kc);
      #pragma unroll
      for (int bb = 0; bb < 32; bb++) {
        float4 xv = *reinterpret_cast<const float4*>(X2 + (size_t)bb * ldx2 + kc);
        acc0[bb] += w0.x * xv.x + w0.y * xv.y + w0.z * xv.z + w0.w * xv.w;
        acc1[bb] += w1.x * xv.x + w1.y * xv.y + w1.z * xv.z + w1.w * xv.w;
      }
    }
  }
  #pragma unroll
  for (int off = 1; off < 64; off <<= 1)
    #pragma unroll
    for (int bb = 0; bb < 32; bb++) {
      acc0[bb] += __shfl_xor(acc0[bb], off, 64);
      acc1[bb] += __shfl_xor(acc1[bb], off, 64);
    }
  float r0 = 0.f, r1 = 0.f;
  #pragma unroll
  for (int bb = 0; bb < 32; bb++) {
    if ((lane & 31) == bb) { r0 = acc0[bb]; r1 = acc1[bb]; }
  }
  if (lane < 32) {
    float bias0 = (b1 ? b1[j0] : 0.f) + (b2 ? b2[j0] : 0.f);
    float bias1 = (b1 ? b1[j0 + 1] : 0.f) + (b2 ? b2[j0 + 1] : 0.f);
    float v0 = r0 + bias0, v1 = r1 + bias1;
    if (act == 1) { v0 = fast_tanh(v0); v1 = fast_tanh(v1); }
    out[(size_t)lane * ldo + j0]     = v0;
    out[(size_t)lane * ldo + j0 + 1] = v1;
  }
}

// ---------- build xc = [att_ours, att_theirs, additional, h0[idx]] ; combines att partials ----------
__global__ __launch_bounds__(256) void buildx_k(
    const float* __restrict__ att_part, const float* __restrict__ addl,
    const float* __restrict__ h0, const int* __restrict__ idx, float* __restrict__ xc){
  const int b = blockIdx.y;
  const int k = blockIdx.x * 256 + threadIdx.x;
  if (k >= 3328) return;
  float v;
  if (k < 2048) {
    int g = (k < 1024) ? b : (32 + b);
    int d = k & 1023;
    v = 0.f;
    #pragma unroll
    for (int c = 0; c < 8; c++)
      v += att_part[((size_t)c * 64 + g) * D_ + d];
  }
  else if (k < 2304) v = addl[b * ADD_ + (k - 2048)];
  else               v = h0[(size_t)idx[b] * H_ + (k - 2304)];
  xc[(size_t)b * 3328 + k] = v;
}

// ---------- LSTM pointwise ----------
__global__ __launch_bounds__(256) void lstm_pw(
    const float* __restrict__ gates, const float* __restrict__ c_prev,
    const int* __restrict__ idx, float* __restrict__ h_out, float* __restrict__ c_out,
    float* __restrict__ xc_next, int xld, const float* __restrict__ gather_src){
  const int b = blockIdx.y;
  const int h = blockIdx.x * 256 + threadIdx.x;
  const int ib = idx[b];
  const float gi = gates[(size_t)b * 4096 + h];
  const float gf = gates[(size_t)b * 4096 + 1024 + h];
  const float gg = gates[(size_t)b * 4096 + 2048 + h];
  const float go = gates[(size_t)b * 4096 + 3072 + h];
  const float cp = c_prev[(size_t)ib * H_ + h];
  const float i = fast_sig(gi), f = fast_sig(gf), o = fast_sig(go);
  const float gt = fast_tanh(gg);
  const float cn = f * cp + i * gt;
  const float hn = o * fast_tanh(cn);
  h_out[(size_t)ib * H_ + h] = hn;
  c_out[(size_t)ib * H_ + h] = cn;
  xc_next[(size_t)b * xld + h] = hn;
  if (gather_src) xc_next[(size_t)b * xld + H_ + h] = gather_src[(size_t)ib * H_ + h];
}

extern "C" void kernel_launch(void* const* d_in, const int* in_sizes, int n_in,
                              void* d_out, int out_size, void* d_ws, size_t ws_size,
                              hipStream_t stream){
  const float* seq_ours   = (const float*)d_in[0];
  const int*   len_ours   = (const int*)d_in[1];
  const float* seq_theirs = (const float*)d_in[2];
  const int*   len_theirs = (const int*)d_in[3];
  const float* ctx        = (const float*)d_in[4];
  const float* addl       = (const float*)d_in[5];
  const float* h0 = (const float*)d_in[6];
  const float* c0 = (const float*)d_in[7];
  const float* h1 = (const float*)d_in[8];
  const float* c1 = (const float*)d_in[9];
  const int*   idx = (const int*)d_in[10];
  const float* Wh  = (const float*)d_in[11];
  const float* Wc  = (const float*)d_in[12];
  const float* v   = (const float*)d_in[13];
  const float* Wih0 = (const float*)d_in[14];
  const float* Whh0 = (const float*)d_in[15];
  const float* bih0 = (const float*)d_in[16];
  const float* bhh0 = (const float*)d_in[17];
  const float* Wih1 = (const float*)d_in[18];
  const float* Whh1 = (const float*)d_in[19];
  const float* bih1 = (const float*)d_in[20];
  const float* bhh1 = (const float*)d_in[21];
  const float* Wout = (const float*)d_in[22];
  const float* bout = (const float*)d_in[23];

  float* out = (float*)d_out;
  char* ws = (char*)d_ws;
  float*    ca     = (float*)(ws + 0);         // 32x1024
  float*    sraw   = (float*)(ws + 131072);    // 64x2048
  float*    p      = (float*)(ws + 655360);    // 64x2048
  float*    xc     = (float*)(ws + 1441792);   // 32x3328
  float*    gates0 = (float*)(ws + 1867776);   // 32x4096
  float*    xc1    = (float*)(ws + 2392064);   // 32x2048
  float*    gates1 = (float*)(ws + 2654208);   // 32x4096
  float*    xc2    = (float*)(ws + 3178496);   // 32x1024
  ushort_t* whbf   = (ushort_t*)(ws + 3309568);// 1024x1024 bf16 (2 MB)
  float*    att_part = (float*)(ws + 3309568); // [8][64][1024] f32 — ALIASES whbf (dead after score)
  ushort_t* bfA    = (ushort_t*)(ws + 5406720);// 2x32x2048x1024 bf16 (268435456 B)

  const size_t NEED = 5406720ull + 268435456ull;   // same footprint as round 2 (known-safe)
  const bool precvt = ws_size >= NEED;

  hipMemsetAsync(sraw, 0, 64 * 2048 * 4, stream);
  cvt16_k<<<256, 256, 0, stream>>>(Wh, whbf, 65536);
  if (precvt){
    cvt16_k<<<16384, 256, 0, stream>>>(seq_theirs, bfA,            4194304);
    cvt16_k<<<16384, 256, 0, stream>>>(seq_ours,   bfA + 67108864, 4194304);
  }
  gemm_small<<<128, 256, 0, stream>>>(ctx, 1024, Wc, 1024, nullptr, 0, nullptr, 0,
                                      nullptr, nullptr, ca, 1024, 1024, 0);
  if (precvt)
    score_gemm<true><<<8192, 256, 0, stream>>>(
        seq_theirs, seq_ours, bfA, whbf, ca, v, sraw);
  else
    score_gemm<false><<<8192, 256, 0, stream>>>(
        seq_theirs, seq_ours, bfA, whbf, ca, v, sraw);
  softmax_k<<<64, 256, 0, stream>>>(sraw, len_theirs, len_ours, p, out);
  if (precvt)
    att_k<true><<<dim3(64, 8), 256, 0, stream>>>(seq_theirs, seq_ours, bfA, p, att_part);
  else
    att_k<false><<<dim3(64, 8), 256, 0, stream>>>(seq_theirs, seq_ours, bfA, p, att_part);
  buildx_k<<<dim3(13, 32), 256, 0, stream>>>(att_part, addl, h0, idx, xc);
  gemm_small<<<512, 256, 0, stream>>>(xc, 3328, Wih0, 2304, xc + 2304, 3328, Whh0, 1024,
                                      bih0, bhh0, gates0, 4096, 4096, 0);
  lstm_pw<<<dim3(4, 32), 256, 0, stream>>>(gates0, c0, idx, out + 32768, out + 65536,
                                           xc1, 2048, h1);
  gemm_small<<<512, 256, 0, stream>>>(xc1, 2048, Wih1, 1024, xc1 + 1024, 2048, Whh1, 1024,
                                      bih1, bhh1, gates1, 4096, 4096, 0);
  lstm_pw<<<dim3(4, 32), 256, 0, stream>>>(gates1, c1, idx, out + 98304, out + 131072,
                                           xc2, 1024, nullptr);
  gemm_small<<<128, 256, 0, stream>>>(xc2, 1024, Wout, 1024, nullptr, 0, nullptr, 0,
                                      bout, nullptr, out, 1024, 1024, 1);
}